// Round 7
// baseline (398.108 us; speedup 1.0000x reference)
//
#include <hip/hip_runtime.h>
#include <hip/hip_bf16.h>

#define NN 100000   // nodes
#define NE 1600000  // edges
#define NG 1000     // graphs
#define NBK 196     // dst buckets of 512 nodes (196*512 >= NN)
#define BSH 9       // bucket shift
#define SLOT 10240  // slack region per bucket (mean 8192 + 4-align padding <= ~10000)

typedef short short8 __attribute__((ext_vector_type(8)));
typedef float f32x4 __attribute__((ext_vector_type(4)));

static inline int cdiv(int a, int b) { return (a + b - 1) / b; }

// f32 -> bf16 (RNE) and helpers
__device__ __forceinline__ unsigned short f2b(float f) {
    unsigned int u = __float_as_uint(f);
    u += 0x7fff + ((u >> 16) & 1);
    return (unsigned short)(u >> 16);
}
__device__ __forceinline__ unsigned int pack2(float lo, float hi) {
    return (unsigned int)f2b(lo) | ((unsigned int)f2b(hi) << 16);
}
__device__ __forceinline__ float bf_lo(unsigned int v) { return __uint_as_float(v << 16); }
__device__ __forceinline__ float bf_hi(unsigned int v) { return __uint_as_float(v & 0xffff0000u); }

// -------------------------------------------------------- cursor init
__global__ __launch_bounds__(256) void k_ginit(int* __restrict__ gcur) {
    int t = threadIdx.x;
    if (t < NBK) gcur[t] = t * SLOT;
}

// -------------------------------------------------------- two-phase binning
__global__ __launch_bounds__(256) void k_bin2(const int* __restrict__ row,
                                              const int* __restrict__ col,
                                              int* __restrict__ gcur,
                                              unsigned int* __restrict__ tmp) {
    __shared__ int cnt[NBK];
    __shared__ int gbase[NBK];
    int t = threadIdx.x;
    if (t < NBK) cnt[t] = 0;
    __syncthreads();
    const int q0 = blockIdx.x * 1000;  // int4 index base (4000 edges)
    const int4* col4 = (const int4*)col;
    const int4* row4 = (const int4*)row;
#pragma unroll
    for (int it = 0; it < 4; it++) {
        int idx = it * 256 + t;
        if (idx < 1000) {
            int4 c = col4[q0 + idx];
            atomicAdd(&cnt[c.x >> BSH], 1);
            atomicAdd(&cnt[c.y >> BSH], 1);
            atomicAdd(&cnt[c.z >> BSH], 1);
            atomicAdd(&cnt[c.w >> BSH], 1);
        }
    }
    __syncthreads();
    if (t < NBK) {
        gbase[t] = atomicAdd(&gcur[t], cnt[t]);
        cnt[t] = 0;  // becomes local cursor
    }
    __syncthreads();
#pragma unroll
    for (int it = 0; it < 4; it++) {
        int idx = it * 256 + t;
        if (idx < 1000) {
            int4 c = col4[q0 + idx];
            int4 r = row4[q0 + idx];
            int d, s, b, p;
            d = c.x; s = r.x; b = d >> BSH; p = atomicAdd(&cnt[b], 1);
            tmp[gbase[b] + p] = ((unsigned int)(d & 511) << 17) | (unsigned int)s;
            d = c.y; s = r.y; b = d >> BSH; p = atomicAdd(&cnt[b], 1);
            tmp[gbase[b] + p] = ((unsigned int)(d & 511) << 17) | (unsigned int)s;
            d = c.z; s = r.z; b = d >> BSH; p = atomicAdd(&cnt[b], 1);
            tmp[gbase[b] + p] = ((unsigned int)(d & 511) << 17) | (unsigned int)s;
            d = c.w; s = r.w; b = d >> BSH; p = atomicAdd(&cnt[b], 1);
            tmp[gbase[b] + p] = ((unsigned int)(d & 511) << 17) | (unsigned int)s;
        }
    }
}

// -------------------------------------------------------- per-bucket CSR
// per-dst degree count, 4-aligned local scan -> off/deg/dinv, then permute.
// each node's segment start is 16B-aligned so k_agg can int4-load indices.
__global__ __launch_bounds__(256) void k_bucket(const unsigned int* __restrict__ tmp,
                                                const int* __restrict__ gcur,
                                                int* __restrict__ off,
                                                int* __restrict__ degw,
                                                float* __restrict__ dinv,
                                                int* __restrict__ csr_src) {
    __shared__ int cnt[512];
    __shared__ int loff[512];
    __shared__ int sh[256];
    int b = blockIdx.x, t = threadIdx.x;
    int j0 = b << BSH;
    int nd = min(512, NN - j0);
    int rb = b * SLOT;
    int m = gcur[b] - rb;
    cnt[t] = 0; cnt[t + 256] = 0;
    __syncthreads();
    for (int i = t; i < m; i += 256)
        atomicAdd(&cnt[tmp[rb + i] >> 17], 1);
    __syncthreads();
    int r0 = cnt[2 * t], r1 = cnt[2 * t + 1];
    int p0 = (r0 + 3) & ~3, p1 = (r1 + 3) & ~3;  // pad to 4-entry alignment
    int ts = p0 + p1;
    sh[t] = ts;
    __syncthreads();
    for (int d = 1; d < 256; d <<= 1) {
        int u = (t >= d) ? sh[t - d] : 0;
        __syncthreads();
        sh[t] += u;
        __syncthreads();
    }
    int ex = sh[t] - ts;
    loff[2 * t] = ex;
    loff[2 * t + 1] = ex + p0;
    __syncthreads();
    for (int j = t; j < nd; j += 256) {
        int o = rb + loff[j];
        int dg = cnt[j];
        off[j0 + j] = o;
        degw[j0 + j] = dg;
        dinv[j0 + j] = rsqrtf((float)(dg + 1));  // +1 self-loop
        cnt[j] = o;  // becomes cursor
    }
    __syncthreads();
    for (int i = t; i < m; i += 256) {
        unsigned int e = tmp[rb + i];
        int d = e >> 17;
        int s = (int)(e & 0x1FFFFu);
        int p = atomicAdd(&cnt[d], 1);
        csr_src[p] = s;
    }
}

// ---------------------------------------------------------------- cast x->bf16
__global__ void k_cast(const float* __restrict__ X, uint* __restrict__ O) {
    int i = blockIdx.x * 256 + threadIdx.x;  // 8 floats each
    const float4* X4 = (const float4*)X;
    float4 v0 = X4[i * 2], v1 = X4[i * 2 + 1];
    uint4 o;
    o.x = pack2(v0.x, v0.y); o.y = pack2(v0.z, v0.w);
    o.z = pack2(v1.x, v1.y); o.w = pack2(v1.z, v1.w);
    ((uint4*)O)[i] = o;
}

// ---------------------------------------------------------------- W transpose
// Wt[n][k] = bf16(W[k][n]); one block per output row. grid 256 = both matrices.
__global__ __launch_bounds__(128) void k_prepW(const float* __restrict__ W1,
                                               const float* __restrict__ W2,
                                               unsigned short* __restrict__ Wt1,
                                               unsigned short* __restrict__ Wt2) {
    int b = blockIdx.x, t = threadIdx.x;
    const float* W = (b < 128) ? W1 : W2;
    unsigned short* Wt = (b < 128) ? Wt1 : Wt2;
    int n = b & 127;
    Wt[n * 128 + t] = f2b(W[t * 128 + n]);
}

// ---------------------------------------------------------------- MFMA GEMM
// Hs[r][c] = dinv[r] * sum_k A[r][k] * Wt[c][k]   (A bf16, Wt bf16 pre-transposed)
// LDS-free: B fragments are contiguous 16B loads from L1/L2-resident Wt.
__global__ __launch_bounds__(256) void k_gemm(const unsigned short* __restrict__ A,
                                              const unsigned short* __restrict__ Wt,
                                              const float* __restrict__ dinv,
                                              unsigned short* __restrict__ Hs) {
    int t = threadIdx.x;
    int lane = t & 63, wid = t >> 6;
    int n16 = lane & 15, quad = lane >> 4;
    int row_base = blockIdx.x * 128 + wid * 32;

    short8 a[2][4];
#pragma unroll
    for (int rt = 0; rt < 2; rt++) {
        int r = row_base + rt * 16 + n16;
        if (r > NN - 1) r = NN - 1;
        const unsigned short* ap = A + (size_t)r * 128 + quad * 8;
#pragma unroll
        for (int ks = 0; ks < 4; ks++)
            a[rt][ks] = *(const short8*)(ap + ks * 32);
    }

    f32x4 acc[2][8];
#pragma unroll
    for (int rt = 0; rt < 2; rt++)
#pragma unroll
        for (int ct = 0; ct < 8; ct++)
            acc[rt][ct] = (f32x4){0.f, 0.f, 0.f, 0.f};

#pragma unroll
    for (int ks = 0; ks < 4; ks++) {
#pragma unroll
        for (int ct = 0; ct < 8; ct++) {
            short8 b = *(const short8*)(Wt + (ct * 16 + n16) * 128 + ks * 32 + quad * 8);
            acc[0][ct] = __builtin_amdgcn_mfma_f32_16x16x32_bf16(a[0][ks], b, acc[0][ct], 0, 0, 0);
            acc[1][ct] = __builtin_amdgcn_mfma_f32_16x16x32_bf16(a[1][ks], b, acc[1][ct], 0, 0, 0);
        }
    }

#pragma unroll
    for (int rt = 0; rt < 2; rt++) {
#pragma unroll
        for (int reg = 0; reg < 4; reg++) {
            int row = row_base + rt * 16 + quad * 4 + reg;
            if (row < NN) {
                float di = dinv[row];
                unsigned short* hp = Hs + (size_t)row * 128 + n16;
#pragma unroll
                for (int ct = 0; ct < 8; ct++)
                    hp[ct * 16] = f2b(acc[rt][ct][reg] * di);
            }
        }
    }
}

// ---------------------------------------------------------------- aggregation
// out[i] = relu( dinv[i] * (Hs[i] + sum_e Hs[src_e]) + bias ), bf16 out.
// 4 subgroups x 16 lanes; 16 edges/iter, int4 index load (segments 16B-aligned),
// float2 accumulators to encourage v_pk_add_f32.
__global__ __launch_bounds__(256) void k_agg(const uint4* __restrict__ H4,
                                             const int* __restrict__ off,
                                             const int* __restrict__ degw,
                                             const int* __restrict__ csr_src,
                                             const float* __restrict__ dinv,
                                             const float* __restrict__ bias,
                                             uint4* __restrict__ out4) {
    int node = blockIdx.x * 4 + (threadIdx.x >> 6);
    int lane = threadIdx.x & 63;
    int sub = lane >> 4, li = lane & 15;
    float2 A0 = {0.f, 0.f}, A1 = {0.f, 0.f}, A2 = {0.f, 0.f}, A3 = {0.f, 0.f};
    if (sub == 0) {  // self term (already dinv-scaled)
        uint4 v = H4[(size_t)node * 16 + li];
        A0.x = bf_lo(v.x); A0.y = bf_hi(v.x); A1.x = bf_lo(v.y); A1.y = bf_hi(v.y);
        A2.x = bf_lo(v.z); A2.y = bf_hi(v.z); A3.x = bf_lo(v.w); A3.y = bf_hi(v.w);
    }
    int e0 = off[node], e1 = e0 + degw[node];
    int e = e0;
    for (; e + 16 <= e1; e += 16) {
        int4 sv = *(const int4*)(csr_src + e + sub * 4);  // subgroup's 4 edges
        uint4 w0 = H4[(size_t)sv.x * 16 + li];
        uint4 w1 = H4[(size_t)sv.y * 16 + li];
        uint4 w2 = H4[(size_t)sv.z * 16 + li];
        uint4 w3 = H4[(size_t)sv.w * 16 + li];
        A0.x += (bf_lo(w0.x) + bf_lo(w1.x)) + (bf_lo(w2.x) + bf_lo(w3.x));
        A0.y += (bf_hi(w0.x) + bf_hi(w1.x)) + (bf_hi(w2.x) + bf_hi(w3.x));
        A1.x += (bf_lo(w0.y) + bf_lo(w1.y)) + (bf_lo(w2.y) + bf_lo(w3.y));
        A1.y += (bf_hi(w0.y) + bf_hi(w1.y)) + (bf_hi(w2.y) + bf_hi(w3.y));
        A2.x += (bf_lo(w0.z) + bf_lo(w1.z)) + (bf_lo(w2.z) + bf_lo(w3.z));
        A2.y += (bf_hi(w0.z) + bf_hi(w1.z)) + (bf_hi(w2.z) + bf_hi(w3.z));
        A3.x += (bf_lo(w0.w) + bf_lo(w1.w)) + (bf_lo(w2.w) + bf_lo(w3.w));
        A3.y += (bf_hi(w0.w) + bf_hi(w1.w)) + (bf_hi(w2.w) + bf_hi(w3.w));
    }
    for (; e + 8 <= e1; e += 8) {
        int2 sv = *(const int2*)(csr_src + e + sub * 2);
        uint4 wA = H4[(size_t)sv.x * 16 + li];
        uint4 wB = H4[(size_t)sv.y * 16 + li];
        A0.x += bf_lo(wA.x) + bf_lo(wB.x); A0.y += bf_hi(wA.x) + bf_hi(wB.x);
        A1.x += bf_lo(wA.y) + bf_lo(wB.y); A1.y += bf_hi(wA.y) + bf_hi(wB.y);
        A2.x += bf_lo(wA.z) + bf_lo(wB.z); A2.y += bf_hi(wA.z) + bf_hi(wB.z);
        A3.x += bf_lo(wA.w) + bf_lo(wB.w); A3.y += bf_hi(wA.w) + bf_hi(wB.w);
    }
    for (; e < e1; e += 4) {
        int ee = e + sub;
        if (ee < e1) {
            int s = csr_src[ee];
            uint4 w = H4[(size_t)s * 16 + li];
            A0.x += bf_lo(w.x); A0.y += bf_hi(w.x);
            A1.x += bf_lo(w.y); A1.y += bf_hi(w.y);
            A2.x += bf_lo(w.z); A2.y += bf_hi(w.z);
            A3.x += bf_lo(w.w); A3.y += bf_hi(w.w);
        }
    }
#pragma unroll
    for (int d = 16; d <= 32; d <<= 1) {
        A0.x += __shfl_xor(A0.x, d); A0.y += __shfl_xor(A0.y, d);
        A1.x += __shfl_xor(A1.x, d); A1.y += __shfl_xor(A1.y, d);
        A2.x += __shfl_xor(A2.x, d); A2.y += __shfl_xor(A2.y, d);
        A3.x += __shfl_xor(A3.x, d); A3.y += __shfl_xor(A3.y, d);
    }
    if (sub == 0) {
        float di = dinv[node];
        const float4* b4 = (const float4*)bias;
        float4 bA = b4[li * 2], bB = b4[li * 2 + 1];
        float r0 = fmaxf(fmaf(di, A0.x, bA.x), 0.f);
        float r1 = fmaxf(fmaf(di, A0.y, bA.y), 0.f);
        float r2 = fmaxf(fmaf(di, A1.x, bA.z), 0.f);
        float r3 = fmaxf(fmaf(di, A1.y, bA.w), 0.f);
        float r4 = fmaxf(fmaf(di, A2.x, bB.x), 0.f);
        float r5 = fmaxf(fmaf(di, A2.y, bB.y), 0.f);
        float r6 = fmaxf(fmaf(di, A3.x, bB.z), 0.f);
        float r7 = fmaxf(fmaf(di, A3.y, bB.w), 0.f);
        uint4 o;
        o.x = pack2(r0, r1); o.y = pack2(r2, r3);
        o.z = pack2(r4, r5); o.w = pack2(r6, r7);
        out4[(size_t)node * 16 + li] = o;
    }
}

// ---------------------------------------------------------------- mean pool
__global__ __launch_bounds__(128) void k_pool(const unsigned short* __restrict__ A,
                                              const int* __restrict__ batch,
                                              float* __restrict__ emb) {
    int g = blockIdx.x;
    int c = threadIdx.x;
    int lo = 0, hi = NN;
    while (lo < hi) { int m = (lo + hi) >> 1; if (batch[m] < g) lo = m + 1; else hi = m; }
    int start = lo;
    hi = NN;
    while (lo < hi) { int m = (lo + hi) >> 1; if (batch[m] < g + 1) lo = m + 1; else hi = m; }
    int end = lo;
    float s = 0.f;
    for (int i = start; i < end; i++)
        s += __uint_as_float((unsigned int)A[(size_t)i * 128 + c] << 16);
    int cnt = end - start;
    emb[g * 128 + c] = s / (float)max(cnt, 1);
}

// ---------------------------------------------------------------- head MLP
__global__ __launch_bounds__(128) void k_head(const float* __restrict__ emb,
                                              const float* __restrict__ u,
                                              const float* __restrict__ Wh1,
                                              const float* __restrict__ bh1,
                                              const float* __restrict__ Wh2,
                                              const float* __restrict__ bh2,
                                              float* __restrict__ out) {
    __shared__ float hc[192];
    __shared__ float tt[128];
    int g = blockIdx.x, t = threadIdx.x;
    hc[t] = emb[g * 128 + t];
    if (t < 64) hc[128 + t] = u[g * 64 + t];
    __syncthreads();
    float acc = bh1[t];
    for (int k = 0; k < 192; k++) acc = fmaf(hc[k], Wh1[k * 128 + t], acc);
    tt[t] = fmaxf(acc, 0.f);
    __syncthreads();
    if (t < 2) {
        float o = bh2[t];
        for (int c2 = 0; c2 < 128; c2++) o = fmaf(tt[c2], Wh2[c2 * 2 + t], o);
        out[g * 2 + t] = o;
    }
}

// ---------------------------------------------------------------- launcher
extern "C" void kernel_launch(void* const* d_in, const int* in_sizes, int n_in,
                              void* d_out, int out_size, void* d_ws, size_t ws_size,
                              hipStream_t stream) {
    const float* x   = (const float*)d_in[0];
    const int*   ei  = (const int*)d_in[1];
    const int*   row = ei;        // edge_index[0] = src
    const int*   col = ei + NE;   // edge_index[1] = dst
    const float* u   = (const float*)d_in[2];
    const int*   batch = (const int*)d_in[3];
    const float* W1  = (const float*)d_in[5];
    const float* b1  = (const float*)d_in[6];
    const float* W2  = (const float*)d_in[7];
    const float* b2  = (const float*)d_in[8];
    const float* Wh1 = (const float*)d_in[9];
    const float* bh1 = (const float*)d_in[10];
    const float* Wh2 = (const float*)d_in[11];
    const float* bh2 = (const float*)d_in[12];
    float* out = (float*)d_out;

    char* ws = (char*)d_ws;
    size_t o = 0;
    auto alloc = [&](size_t bytes) -> void* {
        void* p = ws + o;
        o += (bytes + 511) & ~(size_t)511;
        return p;
    };
    unsigned short* Xbf = (unsigned short*)alloc((size_t)NN * 128 * 2);  // also A1 (aliased)
    unsigned short* Hsb = (unsigned short*)alloc((size_t)NN * 128 * 2);
    unsigned short* A2b = (unsigned short*)alloc((size_t)NN * 128 * 2);
    unsigned short* Wt1 = (unsigned short*)alloc((size_t)128 * 128 * 2);
    unsigned short* Wt2 = (unsigned short*)alloc((size_t)128 * 128 * 2);
    float* dinv   = (float*)alloc((size_t)NN * 4);
    int*   off    = (int*)alloc((size_t)NN * 4);
    int*   degw   = (int*)alloc((size_t)NN * 4);
    int*   csr_src= (int*)alloc((size_t)NBK * SLOT * 4);
    unsigned int* tmp = (unsigned int*)alloc((size_t)NBK * SLOT * 4);
    int*   gcur   = (int*)alloc((size_t)256 * 4);
    float* emb    = (float*)alloc((size_t)NG * 128 * 4);
    unsigned short* A1bf = Xbf;

    // --- CSR build via slack-region binning ---
    k_ginit<<<1, 256, 0, stream>>>(gcur);
    k_bin2<<<400, 256, 0, stream>>>(row, col, gcur, tmp);
    k_bucket<<<NBK, 256, 0, stream>>>(tmp, gcur, off, degw, dinv, csr_src);

    // --- weight transpose + input cast ---
    k_prepW<<<256, 128, 0, stream>>>(W1, W2, Wt1, Wt2);
    k_cast<<<NN * 128 / (256 * 8), 256, 0, stream>>>(x, (uint*)Xbf);

    // --- layer 1 ---
    k_gemm<<<cdiv(NN, 128), 256, 0, stream>>>(Xbf, Wt1, dinv, Hsb);
    k_agg<<<NN / 4, 256, 0, stream>>>((const uint4*)Hsb, off, degw, csr_src,
                                      dinv, b1, (uint4*)A1bf);
    // --- layer 2 ---
    k_gemm<<<cdiv(NN, 128), 256, 0, stream>>>(A1bf, Wt2, dinv, Hsb);
    k_agg<<<NN / 4, 256, 0, stream>>>((const uint4*)Hsb, off, degw, csr_src,
                                      dinv, b2, (uint4*)A2b);

    // --- mean pool + head ---
    k_pool<<<NG, 128, 0, stream>>>(A2b, batch, emb);
    k_head<<<NG, 128, 0, stream>>>(emb, u, Wh1, bh1, Wh2, bh2, out);
}

// Round 8
// 326.565 us; speedup vs baseline: 1.2191x; 1.2191x over previous
//
#include <hip/hip_runtime.h>
#include <hip/hip_bf16.h>

#define NN 100000   // nodes
#define NE 1600000  // edges
#define NG 1000     // graphs
#define NBK 196     // dst buckets of 512 nodes (196*512 >= NN)
#define BSH 9       // bucket shift
#define SLOT 10240  // slack region per bucket (mean 8192 + 4-align padding)

typedef short short8 __attribute__((ext_vector_type(8)));
typedef float f32x4 __attribute__((ext_vector_type(4)));

static inline int cdiv(int a, int b) { return (a + b - 1) / b; }

// f32 -> bf16 (RNE) and helpers
__device__ __forceinline__ unsigned short f2b(float f) {
    unsigned int u = __float_as_uint(f);
    u += 0x7fff + ((u >> 16) & 1);
    return (unsigned short)(u >> 16);
}
__device__ __forceinline__ unsigned int pack2(float lo, float hi) {
    return (unsigned int)f2b(lo) | ((unsigned int)f2b(hi) << 16);
}
__device__ __forceinline__ float bf_lo(unsigned int v) { return __uint_as_float(v << 16); }
__device__ __forceinline__ float bf_hi(unsigned int v) { return __uint_as_float(v & 0xffff0000u); }

// ------------------------------------------------- prep: W transpose + cursor init
// blocks 0..127: Wt[n][k] = bf16(W[k][n]) for both weight matrices (n = blockIdx)
// block 128: init per-bucket cursors.
__global__ __launch_bounds__(256) void k_prep(const float* __restrict__ W1,
                                              const float* __restrict__ W2,
                                              unsigned short* __restrict__ Wt1,
                                              unsigned short* __restrict__ Wt2,
                                              int* __restrict__ gcur) {
    int b = blockIdx.x, t = threadIdx.x;
    if (b < 128) {
        if (t < 128) Wt1[b * 128 + t] = f2b(W1[t * 128 + b]);
        else         Wt2[b * 128 + (t - 128)] = f2b(W2[(t - 128) * 128 + b]);
    } else if (t < NBK) {
        gcur[t] = t * SLOT;
    }
}

// -------------------------------------------------------- two-phase binning
__global__ __launch_bounds__(256) void k_bin2(const int* __restrict__ row,
                                              const int* __restrict__ col,
                                              int* __restrict__ gcur,
                                              unsigned int* __restrict__ tmp) {
    __shared__ int cnt[NBK];
    __shared__ int gbase[NBK];
    int t = threadIdx.x;
    if (t < NBK) cnt[t] = 0;
    __syncthreads();
    const int q0 = blockIdx.x * 1000;  // int4 index base (4000 edges)
    const int4* col4 = (const int4*)col;
    const int4* row4 = (const int4*)row;
#pragma unroll
    for (int it = 0; it < 4; it++) {
        int idx = it * 256 + t;
        if (idx < 1000) {
            int4 c = col4[q0 + idx];
            atomicAdd(&cnt[c.x >> BSH], 1);
            atomicAdd(&cnt[c.y >> BSH], 1);
            atomicAdd(&cnt[c.z >> BSH], 1);
            atomicAdd(&cnt[c.w >> BSH], 1);
        }
    }
    __syncthreads();
    if (t < NBK) {
        gbase[t] = atomicAdd(&gcur[t], cnt[t]);
        cnt[t] = 0;  // becomes local cursor
    }
    __syncthreads();
#pragma unroll
    for (int it = 0; it < 4; it++) {
        int idx = it * 256 + t;
        if (idx < 1000) {
            int4 c = col4[q0 + idx];
            int4 r = row4[q0 + idx];
            int d, s, b, p;
            d = c.x; s = r.x; b = d >> BSH; p = atomicAdd(&cnt[b], 1);
            tmp[gbase[b] + p] = ((unsigned int)(d & 511) << 17) | (unsigned int)s;
            d = c.y; s = r.y; b = d >> BSH; p = atomicAdd(&cnt[b], 1);
            tmp[gbase[b] + p] = ((unsigned int)(d & 511) << 17) | (unsigned int)s;
            d = c.z; s = r.z; b = d >> BSH; p = atomicAdd(&cnt[b], 1);
            tmp[gbase[b] + p] = ((unsigned int)(d & 511) << 17) | (unsigned int)s;
            d = c.w; s = r.w; b = d >> BSH; p = atomicAdd(&cnt[b], 1);
            tmp[gbase[b] + p] = ((unsigned int)(d & 511) << 17) | (unsigned int)s;
        }
    }
}

// -------------------------------------------------------- per-bucket CSR
// per-dst degree count, 4-aligned local scan -> off/deg/dinv, then permute.
__global__ __launch_bounds__(256) void k_bucket(const unsigned int* __restrict__ tmp,
                                                const int* __restrict__ gcur,
                                                int* __restrict__ off,
                                                int* __restrict__ degw,
                                                float* __restrict__ dinv,
                                                int* __restrict__ csr_src) {
    __shared__ int cnt[512];
    __shared__ int loff[512];
    __shared__ int sh[256];
    int b = blockIdx.x, t = threadIdx.x;
    int j0 = b << BSH;
    int nd = min(512, NN - j0);
    int rb = b * SLOT;
    int m = gcur[b] - rb;
    cnt[t] = 0; cnt[t + 256] = 0;
    __syncthreads();
    for (int i = t; i < m; i += 256)
        atomicAdd(&cnt[tmp[rb + i] >> 17], 1);
    __syncthreads();
    int r0 = cnt[2 * t], r1 = cnt[2 * t + 1];
    int p0 = (r0 + 3) & ~3, p1 = (r1 + 3) & ~3;  // pad to 4-entry alignment
    int ts = p0 + p1;
    sh[t] = ts;
    __syncthreads();
    for (int d = 1; d < 256; d <<= 1) {
        int u = (t >= d) ? sh[t - d] : 0;
        __syncthreads();
        sh[t] += u;
        __syncthreads();
    }
    int ex = sh[t] - ts;
    loff[2 * t] = ex;
    loff[2 * t + 1] = ex + p0;
    __syncthreads();
    for (int j = t; j < nd; j += 256) {
        int o = rb + loff[j];
        int dg = cnt[j];
        off[j0 + j] = o;
        degw[j0 + j] = dg;
        dinv[j0 + j] = rsqrtf((float)(dg + 1));  // +1 self-loop
        cnt[j] = o;  // becomes cursor
    }
    __syncthreads();
    for (int i = t; i < m; i += 256) {
        unsigned int e = tmp[rb + i];
        int d = e >> 17;
        int s = (int)(e & 0x1FFFFu);
        int p = atomicAdd(&cnt[d], 1);
        csr_src[p] = s;
    }
}

// ---------------------------------------------------------------- MFMA GEMM
// Hs[r][c] = dinv[r] * sum_k A[r][k] * Wt[c][k]
// Wt (bf16, pre-transposed) staged to LDS with XOR-16B-chunk swizzle via
// vector copies; fragment reads ds_read_b128 conflict-free (R6-verified).
// AF32: A is f32 (layer-1 input x), packed to bf16 in-register (same f2b).
template <bool AF32>
__global__ __launch_bounds__(256) void k_gemm(const void* __restrict__ Ap,
                                              const unsigned short* __restrict__ Wt,
                                              const float* __restrict__ dinv,
                                              unsigned short* __restrict__ Hs) {
    __shared__ __align__(16) unsigned short Ws[128 * 128];  // 32 KB
    int t = threadIdx.x;
    // stage: 2048 16B chunks, 8 per thread. chunk c of row n -> byte n*256 + ((c^(n&15))<<4)
#pragma unroll
    for (int i = 0; i < 8; i++) {
        int id = t + i * 256;
        int n = id >> 4, c = id & 15;
        *(short8*)((char*)Ws + n * 256 + ((c ^ (n & 15)) << 4)) =
            *(const short8*)(Wt + n * 128 + c * 8);
    }
    __syncthreads();

    int lane = t & 63, wid = t >> 6;
    int n16 = lane & 15, quad = lane >> 4;
    int row_base = blockIdx.x * 128 + wid * 32;

    short8 a[2][4];
#pragma unroll
    for (int rt = 0; rt < 2; rt++) {
        int r = row_base + rt * 16 + n16;
        if (r > NN - 1) r = NN - 1;
        if (AF32) {
            const float* ap = (const float*)Ap + (size_t)r * 128 + quad * 8;
#pragma unroll
            for (int ks = 0; ks < 4; ks++) {
                float4 v0 = *(const float4*)(ap + ks * 32);
                float4 v1 = *(const float4*)(ap + ks * 32 + 4);
                uint4 up;
                up.x = pack2(v0.x, v0.y); up.y = pack2(v0.z, v0.w);
                up.z = pack2(v1.x, v1.y); up.w = pack2(v1.z, v1.w);
                a[rt][ks] = *(short8*)&up;
            }
        } else {
            const unsigned short* ap = (const unsigned short*)Ap + (size_t)r * 128 + quad * 8;
#pragma unroll
            for (int ks = 0; ks < 4; ks++)
                a[rt][ks] = *(const short8*)(ap + ks * 32);
        }
    }

    f32x4 acc[2][8];
#pragma unroll
    for (int rt = 0; rt < 2; rt++)
#pragma unroll
        for (int ct = 0; ct < 8; ct++)
            acc[rt][ct] = (f32x4){0.f, 0.f, 0.f, 0.f};

#pragma unroll
    for (int ks = 0; ks < 4; ks++) {
#pragma unroll
        for (int ct = 0; ct < 8; ct++) {
            short8 b = *(const short8*)((const char*)Ws +
                        (ct * 16 + n16) * 256 + ((((ks << 2) + quad) ^ n16) << 4));
            acc[0][ct] = __builtin_amdgcn_mfma_f32_16x16x32_bf16(a[0][ks], b, acc[0][ct], 0, 0, 0);
            acc[1][ct] = __builtin_amdgcn_mfma_f32_16x16x32_bf16(a[1][ks], b, acc[1][ct], 0, 0, 0);
        }
    }

#pragma unroll
    for (int rt = 0; rt < 2; rt++) {
#pragma unroll
        for (int reg = 0; reg < 4; reg++) {
            int row = row_base + rt * 16 + quad * 4 + reg;
            if (row < NN) {
                float di = dinv[row];
                unsigned short* hp = Hs + (size_t)row * 128 + n16;
#pragma unroll
                for (int ct = 0; ct < 8; ct++)
                    hp[ct * 16] = f2b(acc[rt][ct][reg] * di);
            }
        }
    }
}

// ---------------------------------------------------------------- aggregation
// out[i] = relu( dinv[i] * (Hs[i] + sum_e Hs[src_e]) + bias ), bf16 out.
__global__ __launch_bounds__(256) void k_agg(const uint4* __restrict__ H4,
                                             const int* __restrict__ off,
                                             const int* __restrict__ degw,
                                             const int* __restrict__ csr_src,
                                             const float* __restrict__ dinv,
                                             const float* __restrict__ bias,
                                             uint4* __restrict__ out4) {
    int node = blockIdx.x * 4 + (threadIdx.x >> 6);
    int lane = threadIdx.x & 63;
    int sub = lane >> 4, li = lane & 15;
    float2 A0 = {0.f, 0.f}, A1 = {0.f, 0.f}, A2 = {0.f, 0.f}, A3 = {0.f, 0.f};
    if (sub == 0) {  // self term (already dinv-scaled)
        uint4 v = H4[(size_t)node * 16 + li];
        A0.x = bf_lo(v.x); A0.y = bf_hi(v.x); A1.x = bf_lo(v.y); A1.y = bf_hi(v.y);
        A2.x = bf_lo(v.z); A2.y = bf_hi(v.z); A3.x = bf_lo(v.w); A3.y = bf_hi(v.w);
    }
    int e0 = off[node], e1 = e0 + degw[node];
    int e = e0;
    for (; e + 16 <= e1; e += 16) {
        int4 sv = *(const int4*)(csr_src + e + sub * 4);
        uint4 w0 = H4[(size_t)sv.x * 16 + li];
        uint4 w1 = H4[(size_t)sv.y * 16 + li];
        uint4 w2 = H4[(size_t)sv.z * 16 + li];
        uint4 w3 = H4[(size_t)sv.w * 16 + li];
        A0.x += (bf_lo(w0.x) + bf_lo(w1.x)) + (bf_lo(w2.x) + bf_lo(w3.x));
        A0.y += (bf_hi(w0.x) + bf_hi(w1.x)) + (bf_hi(w2.x) + bf_hi(w3.x));
        A1.x += (bf_lo(w0.y) + bf_lo(w1.y)) + (bf_lo(w2.y) + bf_lo(w3.y));
        A1.y += (bf_hi(w0.y) + bf_hi(w1.y)) + (bf_hi(w2.y) + bf_hi(w3.y));
        A2.x += (bf_lo(w0.z) + bf_lo(w1.z)) + (bf_lo(w2.z) + bf_lo(w3.z));
        A2.y += (bf_hi(w0.z) + bf_hi(w1.z)) + (bf_hi(w2.z) + bf_hi(w3.z));
        A3.x += (bf_lo(w0.w) + bf_lo(w1.w)) + (bf_lo(w2.w) + bf_lo(w3.w));
        A3.y += (bf_hi(w0.w) + bf_hi(w1.w)) + (bf_hi(w2.w) + bf_hi(w3.w));
    }
    for (; e + 8 <= e1; e += 8) {
        int2 sv = *(const int2*)(csr_src + e + sub * 2);
        uint4 wA = H4[(size_t)sv.x * 16 + li];
        uint4 wB = H4[(size_t)sv.y * 16 + li];
        A0.x += bf_lo(wA.x) + bf_lo(wB.x); A0.y += bf_hi(wA.x) + bf_hi(wB.x);
        A1.x += bf_lo(wA.y) + bf_lo(wB.y); A1.y += bf_hi(wA.y) + bf_hi(wB.y);
        A2.x += bf_lo(wA.z) + bf_lo(wB.z); A2.y += bf_hi(wA.z) + bf_hi(wB.z);
        A3.x += bf_lo(wA.w) + bf_lo(wB.w); A3.y += bf_hi(wA.w) + bf_hi(wB.w);
    }
    for (; e < e1; e += 4) {
        int ee = e + sub;
        if (ee < e1) {
            int s = csr_src[ee];
            uint4 w = H4[(size_t)s * 16 + li];
            A0.x += bf_lo(w.x); A0.y += bf_hi(w.x);
            A1.x += bf_lo(w.y); A1.y += bf_hi(w.y);
            A2.x += bf_lo(w.z); A2.y += bf_hi(w.z);
            A3.x += bf_lo(w.w); A3.y += bf_hi(w.w);
        }
    }
#pragma unroll
    for (int d = 16; d <= 32; d <<= 1) {
        A0.x += __shfl_xor(A0.x, d); A0.y += __shfl_xor(A0.y, d);
        A1.x += __shfl_xor(A1.x, d); A1.y += __shfl_xor(A1.y, d);
        A2.x += __shfl_xor(A2.x, d); A2.y += __shfl_xor(A2.y, d);
        A3.x += __shfl_xor(A3.x, d); A3.y += __shfl_xor(A3.y, d);
    }
    if (sub == 0) {
        float di = dinv[node];
        const float4* b4 = (const float4*)bias;
        float4 bA = b4[li * 2], bB = b4[li * 2 + 1];
        float r0 = fmaxf(fmaf(di, A0.x, bA.x), 0.f);
        float r1 = fmaxf(fmaf(di, A0.y, bA.y), 0.f);
        float r2 = fmaxf(fmaf(di, A1.x, bA.z), 0.f);
        float r3 = fmaxf(fmaf(di, A1.y, bA.w), 0.f);
        float r4 = fmaxf(fmaf(di, A2.x, bB.x), 0.f);
        float r5 = fmaxf(fmaf(di, A2.y, bB.y), 0.f);
        float r6 = fmaxf(fmaf(di, A3.x, bB.z), 0.f);
        float r7 = fmaxf(fmaf(di, A3.y, bB.w), 0.f);
        uint4 o;
        o.x = pack2(r0, r1); o.y = pack2(r2, r3);
        o.z = pack2(r4, r5); o.w = pack2(r6, r7);
        out4[(size_t)node * 16 + li] = o;
    }
}

// ------------------------------------------------- fused mean-pool + head MLP
// one block (256 thr) per graph: vectorized segment sum, then the 2-layer head.
__global__ __launch_bounds__(256) void k_poolhead(const unsigned short* __restrict__ A,
                                                  const int* __restrict__ batch,
                                                  const float* __restrict__ u,
                                                  const float* __restrict__ Wh1,
                                                  const float* __restrict__ bh1,
                                                  const float* __restrict__ Wh2,
                                                  const float* __restrict__ bh2,
                                                  float* __restrict__ out) {
    int g = blockIdx.x, t = threadIdx.x;
    // node range of graph g (batch sorted; redundant uniform search)
    int lo = 0, hi = NN;
    while (lo < hi) { int m = (lo + hi) >> 1; if (batch[m] < g) lo = m + 1; else hi = m; }
    int start = lo;
    hi = NN;
    while (lo < hi) { int m = (lo + hi) >> 1; if (batch[m] < g + 1) lo = m + 1; else hi = m; }
    int end = lo;

    int li = t & 15;   // col chunk (8 cols)
    int ri = t >> 4;   // row offset 0..15
    float acc[8] = {0.f, 0.f, 0.f, 0.f, 0.f, 0.f, 0.f, 0.f};
    for (int i = start + ri; i < end; i += 16) {
        uint4 v = *(const uint4*)(A + (size_t)i * 128 + li * 8);
        acc[0] += bf_lo(v.x); acc[1] += bf_hi(v.x);
        acc[2] += bf_lo(v.y); acc[3] += bf_hi(v.y);
        acc[4] += bf_lo(v.z); acc[5] += bf_hi(v.z);
        acc[6] += bf_lo(v.w); acc[7] += bf_hi(v.w);
    }
    // reduce the 4 in-wave row groups
#pragma unroll
    for (int j = 0; j < 8; j++) {
        acc[j] += __shfl_xor(acc[j], 16);
        acc[j] += __shfl_xor(acc[j], 32);
    }
    __shared__ float part[4][128];
    __shared__ float hc[192];
    __shared__ float tt[128];
    int w = t >> 6;
    if ((t & 63) < 16) {
#pragma unroll
        for (int j = 0; j < 8; j++) part[w][li * 8 + j] = acc[j];
    }
    __syncthreads();
    float cntf = (float)max(end - start, 1);
    if (t < 128) {
        hc[t] = (part[0][t] + part[1][t] + part[2][t] + part[3][t]) / cntf;
    } else if (t < 192) {
        hc[t] = u[g * 64 + (t - 128)];
    }
    __syncthreads();
    if (t < 128) {
        float a2 = bh1[t];
        for (int k = 0; k < 192; k++) a2 = fmaf(hc[k], Wh1[k * 128 + t], a2);
        tt[t] = fmaxf(a2, 0.f);
    }
    __syncthreads();
    if (t < 2) {
        float o = bh2[t];
        for (int c2 = 0; c2 < 128; c2++) o = fmaf(tt[c2], Wh2[c2 * 2 + t], o);
        out[g * 2 + t] = o;
    }
}

// ---------------------------------------------------------------- launcher
extern "C" void kernel_launch(void* const* d_in, const int* in_sizes, int n_in,
                              void* d_out, int out_size, void* d_ws, size_t ws_size,
                              hipStream_t stream) {
    const float* x   = (const float*)d_in[0];
    const int*   ei  = (const int*)d_in[1];
    const int*   row = ei;        // edge_index[0] = src
    const int*   col = ei + NE;   // edge_index[1] = dst
    const float* u   = (const float*)d_in[2];
    const int*   batch = (const int*)d_in[3];
    const float* W1  = (const float*)d_in[5];
    const float* b1  = (const float*)d_in[6];
    const float* W2  = (const float*)d_in[7];
    const float* b2  = (const float*)d_in[8];
    const float* Wh1 = (const float*)d_in[9];
    const float* bh1 = (const float*)d_in[10];
    const float* Wh2 = (const float*)d_in[11];
    const float* bh2 = (const float*)d_in[12];
    float* out = (float*)d_out;

    char* ws = (char*)d_ws;
    size_t o = 0;
    auto alloc = [&](size_t bytes) -> void* {
        void* p = ws + o;
        o += (bytes + 511) & ~(size_t)511;
        return p;
    };
    unsigned short* Hsb = (unsigned short*)alloc((size_t)NN * 128 * 2);
    unsigned short* A1b = (unsigned short*)alloc((size_t)NN * 128 * 2);
    unsigned short* A2b = (unsigned short*)alloc((size_t)NN * 128 * 2);
    unsigned short* Wt1 = (unsigned short*)alloc((size_t)128 * 128 * 2);
    unsigned short* Wt2 = (unsigned short*)alloc((size_t)128 * 128 * 2);
    float* dinv   = (float*)alloc((size_t)NN * 4);
    int*   off    = (int*)alloc((size_t)NN * 4);
    int*   degw   = (int*)alloc((size_t)NN * 4);
    int*   csr_src= (int*)alloc((size_t)NBK * SLOT * 4);
    unsigned int* tmp = (unsigned int*)alloc((size_t)NBK * SLOT * 4);
    int*   gcur   = (int*)alloc((size_t)256 * 4);

    // --- prep (W transpose + cursors) & CSR build ---
    k_prep<<<129, 256, 0, stream>>>(W1, W2, Wt1, Wt2, gcur);
    k_bin2<<<400, 256, 0, stream>>>(row, col, gcur, tmp);
    k_bucket<<<NBK, 256, 0, stream>>>(tmp, gcur, off, degw, dinv, csr_src);

    // --- layer 1 (f32 input, in-register bf16 pack) ---
    k_gemm<true><<<cdiv(NN, 128), 256, 0, stream>>>((const void*)x, Wt1, dinv, Hsb);
    k_agg<<<NN / 4, 256, 0, stream>>>((const uint4*)Hsb, off, degw, csr_src,
                                      dinv, b1, (uint4*)A1b);
    // --- layer 2 ---
    k_gemm<false><<<cdiv(NN, 128), 256, 0, stream>>>((const void*)A1b, Wt2, dinv, Hsb);
    k_agg<<<NN / 4, 256, 0, stream>>>((const uint4*)Hsb, off, degw, csr_src,
                                      dinv, b2, (uint4*)A2b);

    // --- fused mean pool + head ---
    k_poolhead<<<NG, 256, 0, stream>>>(A2b, batch, u, Wh1, bh1, Wh2, bh2, out);
}